// Round 12
// baseline (758.559 us; speedup 1.0000x reference)
//
#include <hip/hip_runtime.h>
#include <hip/hip_bf16.h>
#include <hip/hip_fp16.h>

typedef __attribute__((ext_vector_type(8))) short short8;
typedef __attribute__((ext_vector_type(4))) short sh4;
typedef __attribute__((ext_vector_type(8))) _Float16 half8;
typedef __attribute__((ext_vector_type(4))) float floatx4;

__device__ __forceinline__ unsigned short f2bf(float f) {
    unsigned int u = __builtin_bit_cast(unsigned int, f);
    u += 0x7fffu + ((u >> 16) & 1u);
    return (unsigned short)(u >> 16);
}

__device__ __forceinline__ void gl_lds16(const unsigned short* g, unsigned short* l) {
    __builtin_amdgcn_global_load_lds(
        (const __attribute__((address_space(1))) unsigned int*)(const void*)g,
        (__attribute__((address_space(3))) unsigned int*)(void*)l,
        16, 0, 0);
}

#define BM 256
#define BN 256
#define BK 64

// C = A @ B^T, A (M,K) lda, B (N,K) ldb, bf16 K-contiguous row-major.
// 256x256 8-phase template (verified r6/r7: 0 bank conflicts): 8 waves (2Mx4N),
// BK=64, 128KB dbuf LDS, counted vmcnt(4), chunk XOR-swizzle both-sides.
// OMODE: 0=bf16 out, 1=fp32 out, 2=fp16 out.
// bias1!=null: fused-projection region bias select. vstart>=0: V-region -> Vt transposed.
// addmat!=null: per-z fp32 matrix added post-scale (mask fusion for QK^T).
template<int OMODE>
__global__ __launch_bounds__(512, 2)
void gemm_bt(const unsigned short* __restrict__ A,
             const unsigned short* __restrict__ B,
             void* __restrict__ O,
             const float* __restrict__ bias0, const float* __restrict__ bias1,
             const float* __restrict__ bias2,
             int K, int lda, int ldb, int ldo,
             long long aBS, long long bBS, long long oBS,
             float scale, int nby, int vstart,
             unsigned short* __restrict__ Vt, int ldvt,
             const float* __restrict__ addmat, long long addBS)
{
    __shared__ __align__(16) unsigned short lds[2][2][BM * BK]; // 128 KiB

    const int t = threadIdx.x;
    const int lane = t & 63;
    const int w = t >> 6;
    const int wr = w >> 2;       // 0..1 (M)
    const int wc = w & 3;        // 0..3 (N)
    const int lq = lane >> 4;
    const int lr = lane & 15;

    const int nwg = gridDim.x;
    const int swz = (blockIdx.x & 7) * (nwg >> 3) + (blockIdx.x >> 3);
    const int by = swz % nby, bx = swz / nby;
    const size_t m0 = (size_t)bx * BM, n0 = (size_t)by * BN;

    const int z = blockIdx.z;
    const unsigned short* Az = A + (size_t)z * aBS;
    const unsigned short* Bz = B + (size_t)z * bBS;

    const int srow = t >> 3;
    const int scol = ((t & 7) ^ (srow & 7)) << 3;

    floatx4 acc[8][4];
#pragma unroll
    for (int i = 0; i < 8; ++i)
#pragma unroll
        for (int j = 0; j < 4; ++j)
            acc[i][j] = (floatx4){0.f, 0.f, 0.f, 0.f};

    const int NT = K / BK;

    auto stage = [&](int mat, int u, int kt, int buf) {
        const unsigned short* g = (mat ? Bz + (n0 + u * 64 + srow) * (size_t)ldb
                                       : Az + (m0 + u * 64 + srow) * (size_t)lda) + kt + scol;
        gl_lds16(g, &lds[buf][mat][u * 4096 + w * 512]);
    };

#pragma unroll
    for (int u = 0; u < 4; ++u) stage(1, u, 0, 0);
#pragma unroll
    for (int u = 0; u < 4; ++u) stage(0, u, 0, 0);
    if (NT > 1) {
#pragma unroll
        for (int u = 0; u < 4; ++u) stage(1, u, BK, 1);
        asm volatile("s_waitcnt vmcnt(4)" ::: "memory");
    } else {
        asm volatile("s_waitcnt vmcnt(0)" ::: "memory");
    }
    __builtin_amdgcn_s_barrier();
    __builtin_amdgcn_sched_barrier(0);

    for (int tt = 0; tt < NT; ++tt) {
        const int cur = tt & 1, nxt = cur ^ 1;
        const int kt1 = (tt + 1) * BK, kt2 = (tt + 2) * BK;
        short8 bfr[4][2];
#pragma unroll
        for (int p = 0; p < 4; ++p) {
            short8 af[2][2];
            if (p == 0) {
#pragma unroll
                for (int ni = 0; ni < 4; ++ni)
#pragma unroll
                    for (int kk = 0; kk < 2; ++kk) {
                        const int rb = wc * 64 + ni * 16 + lr;
                        const int j = kk * 4 + lq;
                        bfr[ni][kk] = *(const short8*)&lds[cur][1][rb * 64 + ((j ^ (rb & 7)) << 3)];
                    }
            }
#pragma unroll
            for (int mi2 = 0; mi2 < 2; ++mi2)
#pragma unroll
                for (int kk = 0; kk < 2; ++kk) {
                    const int ra = wr * 128 + (2 * p + mi2) * 16 + lr;
                    const int j = kk * 4 + lq;
                    af[mi2][kk] = *(const short8*)&lds[cur][0][ra * 64 + ((j ^ (ra & 7)) << 3)];
                }
            if (p == 0 && tt + 1 < NT) { stage(0, 0, kt1, nxt); stage(0, 1, kt1, nxt); }
            if (p == 1 && tt + 1 < NT) { stage(0, 2, kt1, nxt); stage(0, 3, kt1, nxt); }
            if (p == 2 && tt + 2 < NT) { stage(1, 0, kt2, cur); stage(1, 1, kt2, cur); }
            if (p == 3 && tt + 2 < NT) { stage(1, 2, kt2, cur); stage(1, 3, kt2, cur); }

            __builtin_amdgcn_sched_barrier(0);
            __builtin_amdgcn_s_barrier();
            __builtin_amdgcn_sched_barrier(0);
            __builtin_amdgcn_s_setprio(1);
#pragma unroll
            for (int kk = 0; kk < 2; ++kk)
#pragma unroll
                for (int mi2 = 0; mi2 < 2; ++mi2)
#pragma unroll
                    for (int ni = 0; ni < 4; ++ni)
                        acc[2 * p + mi2][ni] = __builtin_amdgcn_mfma_f32_16x16x32_bf16(
                            af[mi2][kk], bfr[ni][kk], acc[2 * p + mi2][ni], 0, 0, 0);
            __builtin_amdgcn_s_setprio(0);
            __builtin_amdgcn_sched_barrier(0);
            if (p == 3) {
                if (tt < NT - 2) asm volatile("s_waitcnt vmcnt(4)" ::: "memory");
                else             asm volatile("s_waitcnt vmcnt(0)" ::: "memory");
            }
            __builtin_amdgcn_s_barrier();
            __builtin_amdgcn_sched_barrier(0);
        }
    }

    const float* bias = bias0; int cshift = 0;
    if (bias1) {
        const int r = (int)(n0 >> 10);
        bias = (r == 0) ? bias0 : ((r == 1) ? bias1 : bias2);
        cshift = r << 10;
    }
    const float* amz = addmat ? addmat + (size_t)z * addBS : nullptr;

    if (vstart >= 0 && (int)n0 >= vstart) {
        // Transposed write -> Vt[col - vstart][row], per-wave 16KB LDS tile (XOR swizzled)
        unsigned short* lf = &lds[0][0][0] + w * 8192;
        __syncthreads();
#pragma unroll
        for (int mi = 0; mi < 8; ++mi) {
#pragma unroll
            for (int ni = 0; ni < 4; ++ni) {
                const int tc = ni * 16 + lr;
                const int col = (int)n0 + wc * 64 + tc;
                const float cb = bias ? bias[col - cshift] : 0.f;
                const int tr0 = mi * 16 + lq * 4;
                floatx4 v = acc[mi][ni];
                sh4 pk;
#pragma unroll
                for (int r = 0; r < 4; ++r) pk[r] = (short)f2bf(v[r] * scale + cb);
                *(sh4*)&lf[tc * 128 + (tr0 ^ ((tc & 7) << 3))] = pk;
            }
        }
        __syncthreads();
        const int vrow_base = (int)n0 - vstart + wc * 64;
        const size_t colb = m0 + (size_t)wr * 128 + (size_t)(lane & 15) * 8;
#pragma unroll
        for (int i = 0; i < 16; ++i) {
            const int vr = i * 4 + (lane >> 4);
            short8 d = *(const short8*)&lf[vr * 128 + (((lane & 15) * 8) ^ ((vr & 7) << 3))];
            *(short8*)&Vt[(size_t)(vrow_base + vr) * ldvt + colb] = d;
        }
    } else {
#pragma unroll
        for (int mi = 0; mi < 8; ++mi) {
#pragma unroll
            for (int ni = 0; ni < 4; ++ni) {
                const size_t col = n0 + wc * 64 + ni * 16 + lr;
                const float cb = bias ? bias[col - cshift] : 0.f;
                floatx4 v = acc[mi][ni];
#pragma unroll
                for (int r = 0; r < 4; ++r) {
                    const size_t row = m0 + wr * 128 + mi * 16 + lq * 4 + r;
                    float val = v[r] * scale + cb;
                    if (amz) val += amz[row * 2048 + col];
                    const size_t off = (size_t)z * oBS + row * (size_t)ldo + col;
                    if (OMODE == 0)
                        ((unsigned short*)O)[off] = f2bf(val);
                    else if (OMODE == 1)
                        ((float*)O)[off] = val;
                    else {
                        _Float16 h = (_Float16)val;
                        ((unsigned short*)O)[off] = __builtin_bit_cast(unsigned short, h);
                    }
                }
            }
        }
    }
}

// Fused softmax + PV. Block: 32 Q-rows x full D=1024, 16 waves (1024 thr).
// Pre-pass: wave w softmaxes rows w*2, w*2+1 of masked S (fp16) fully in-register,
// writes normalized P bf16 to 128KB LDS (16B-chunk XOR swizzle: chunk ^ (row&7)).
// K-loop (no barriers): P from LDS as A-frags; V frags streamed per-lane from L2
// (batch pinned to XCD by swizzle; Vt slice 4MB = one XCD L2), manual dbuf.
__global__ __launch_bounds__(1024, 1)
void fused_pv(const _Float16* __restrict__ S, const unsigned short* __restrict__ Vt,
              float* __restrict__ out)
{
    __shared__ __align__(16) unsigned short P[32 * 2048]; // 128 KiB

    const int t = threadIdx.x;
    const int lane = t & 63;
    const int w = t >> 6;            // wave 0..15 -> N cols [w*64, w*64+64)
    const int lq = lane >> 4, lr = lane & 15;

    const int bid = blockIdx.x;      // 512 blocks
    const int swz = (bid & 7) * 64 + (bid >> 3);
    const int z = swz >> 6;          // batch == XCD
    const int bx = swz & 63;
    const int m0 = bx * 32;

    const _Float16* Sz = S + (size_t)z * 4194304 + (size_t)m0 * 2048;

    // --- softmax pre-pass: wave handles 2 rows ---
#pragma unroll
    for (int rr = 0; rr < 2; ++rr) {
        const int r = w * 2 + rr;
        const _Float16* row = Sz + (size_t)r * 2048;
        float v[32];
        float mx = -3.4e38f;
#pragma unroll
        for (int i = 0; i < 4; ++i) {
            half8 h = *(const half8*)(row + i * 512 + lane * 8);
#pragma unroll
            for (int j = 0; j < 8; ++j) { v[i * 8 + j] = (float)h[j]; mx = fmaxf(mx, v[i * 8 + j]); }
        }
#pragma unroll
        for (int off = 32; off; off >>= 1) mx = fmaxf(mx, __shfl_xor(mx, off, 64));
        float sum = 0.f;
#pragma unroll
        for (int i = 0; i < 32; ++i) { v[i] = __expf(v[i] - mx); sum += v[i]; }
#pragma unroll
        for (int off = 32; off; off >>= 1) sum += __shfl_xor(sum, off, 64);
        const float inv = 1.0f / sum;
#pragma unroll
        for (int i = 0; i < 4; ++i) {
            short8 pk;
#pragma unroll
            for (int j = 0; j < 8; ++j) pk[j] = (short)f2bf(v[i * 8 + j] * inv);
            const int cc = i * 64 + lane;  // 16B-chunk index 0..255
            *(short8*)((char*)P + r * 4096 + ((cc ^ (r & 7)) << 4)) = pk;
        }
    }
    __syncthreads();

    // --- PV K-loop ---
    floatx4 acc[2][4];
#pragma unroll
    for (int i = 0; i < 2; ++i)
#pragma unroll
        for (int j = 0; j < 4; ++j)
            acc[i][j] = (floatx4){0.f, 0.f, 0.f, 0.f};

    const unsigned short* Vz = Vt + (size_t)z * 2048;
    const int rb_base = w * 64 + lr;

    short8 b0[4][2], b1[4][2];

#define LOADB(TT, BUF)                                                              \
    {                                                                               \
        const size_t kof = (size_t)(TT) * 64 + lq * 8;                              \
        _Pragma("unroll")                                                           \
        for (int ni = 0; ni < 4; ++ni) {                                            \
            const size_t ro = (size_t)(rb_base + ni * 16) * 16384 + kof;            \
            BUF[ni][0] = *(const short8*)(Vz + ro);                                 \
            BUF[ni][1] = *(const short8*)(Vz + ro + 32);                            \
        }                                                                           \
    }

#define COMPUTE(TT, BUF)                                                            \
    {                                                                               \
        short8 af[2][2];                                                            \
        _Pragma("unroll")                                                           \
        for (int mi = 0; mi < 2; ++mi)                                              \
            _Pragma("unroll")                                                       \
            for (int kk = 0; kk < 2; ++kk) {                                        \
                const int ra = mi * 16 + lr;                                        \
                const int cc = (TT) * 8 + kk * 4 + lq;                              \
                af[mi][kk] = *(const short8*)((const char*)P + ra * 4096 +          \
                                              ((cc ^ (ra & 7)) << 4));              \
            }                                                                       \
        _Pragma("unroll")                                                           \
        for (int kk = 0; kk < 2; ++kk)                                              \
            _Pragma("unroll")                                                       \
            for (int mi = 0; mi < 2; ++mi)                                          \
                _Pragma("unroll")                                                   \
                for (int ni = 0; ni < 4; ++ni)                                      \
                    acc[mi][ni] = __builtin_amdgcn_mfma_f32_16x16x32_bf16(          \
                        af[mi][kk], BUF[ni][kk], acc[mi][ni], 0, 0, 0);             \
    }

    LOADB(0, b0);
    for (int tt = 0; tt < 32; tt += 2) {
        LOADB(tt + 1, b1);
        COMPUTE(tt, b0);
        if (tt + 2 < 32) LOADB(tt + 2, b0);
        COMPUTE(tt + 1, b1);
    }
#undef LOADB
#undef COMPUTE

    // epilogue: row = m0 + mi*16 + lq*4 + r, col = w*64 + ni*16 + lr
    float* oz = out + (size_t)z * 2097152;
#pragma unroll
    for (int mi = 0; mi < 2; ++mi) {
#pragma unroll
        for (int ni = 0; ni < 4; ++ni) {
            const int col = w * 64 + ni * 16 + lr;
            floatx4 v = acc[mi][ni];
#pragma unroll
            for (int r = 0; r < 4; ++r) {
                const int row = m0 + mi * 16 + lq * 4 + r;
                oz[(size_t)row * 1024 + col] = v[r];
            }
        }
    }
}

// fp32 -> bf16 for 4 segments in one grid-stride launch
__global__ void cvt4(const float4* __restrict__ s0, ushort4* __restrict__ d0, int n0,
                     const float4* __restrict__ s1, ushort4* __restrict__ d1, int n1,
                     const float4* __restrict__ s2, ushort4* __restrict__ d2, int n2,
                     const float4* __restrict__ s3, ushort4* __restrict__ d3, int n3)
{
    const int total = n0 + n1 + n2 + n3;
    const int stride = gridDim.x * blockDim.x;
    for (int i = blockIdx.x * blockDim.x + threadIdx.x; i < total; i += stride) {
        const float4* s; ushort4* d; int j = i;
        if (j < n0) { s = s0; d = d0; }
        else { j -= n0;
            if (j < n1) { s = s1; d = d1; }
            else { j -= n1;
                if (j < n2) { s = s2; d = d2; }
                else { j -= n2; s = s3; d = d3; }
            }
        }
        float4 f = s[j];
        d[j] = (ushort4){f2bf(f.x), f2bf(f.y), f2bf(f.z), f2bf(f.w)};
    }
}

extern "C" void kernel_launch(void* const* d_in, const int* in_sizes, int n_in,
                              void* d_out, int out_size, void* d_ws, size_t ws_size,
                              hipStream_t stream)
{
    const float* x    = (const float*)d_in[0];
    const float* mask = (const float*)d_in[1];
    const float* Wq   = (const float*)d_in[2];
    const float* bq   = (const float*)d_in[3];
    const float* Wk   = (const float*)d_in[4];
    const float* bk   = (const float*)d_in[5];
    const float* Wv   = (const float*)d_in[6];
    const float* bv   = (const float*)d_in[7];
    float* out = (float*)d_out;

    const size_t MB = 1ull << 20;
    char* ws = (char*)d_ws;
    unsigned short* QKb  = (unsigned short*)(ws);             // 16384x2048 bf16 (Q|K cols), 64MB
    unsigned short* Vt   = (unsigned short*)(ws + 64 * MB);   // 1024x16384 bf16 (V^T), 32MB
    unsigned short* Wcat = (unsigned short*)(ws + 96 * MB);   // 3072x1024 bf16, 6MB
    unsigned short* xb   = (unsigned short*)(ws + 102 * MB);  // 16384x1024 bf16, 32MB
    _Float16* Sb         = (_Float16*)(ws + 134 * MB);        // 8 x 2048 x 2048 fp16 (masked S), 64MB
    (void)ws_size; // r6 evidence: ws >= 230MB; we use 198MB

    cvt4<<<2048, 256, 0, stream>>>(
        (const float4*)x,  (ushort4*)xb,               16384 * 1024 / 4,
        (const float4*)Wq, (ushort4*)Wcat,             1024 * 1024 / 4,
        (const float4*)Wk, (ushort4*)(Wcat + 1048576), 1024 * 1024 / 4,
        (const float4*)Wv, (ushort4*)(Wcat + 2097152), 1024 * 1024 / 4);

    // Fused QKV projection: M=16384, N=3072, K=1024. Cols 0-2047 -> QKb;
    // cols 2048-3071 -> transposed into Vt.
    gemm_bt<0><<<dim3(768, 1, 1), dim3(512), 0, stream>>>(
        xb, Wcat, QKb, bq, bk, bv,
        1024, 1024, 1024, 2048, 0LL, 0LL, 0LL, 1.0f, 12, 2048, Vt, 16384,
        nullptr, 0LL);

    // S = (Q @ K^T) * scale + mask -> fp16, all 8 batches
    const float sscale = 0.03125f; // 1/sqrt(1024)
    gemm_bt<2><<<dim3(64, 1, 8), dim3(512), 0, stream>>>(
        QKb, QKb + 1024, Sb,
        nullptr, nullptr, nullptr,
        1024, 2048, 2048, 2048,
        4194304LL, 4194304LL, 4194304LL, sscale, 8, -1, nullptr, 0,
        mask, 4194304LL);

    // O = softmax(S) @ V, fused (softmax in LDS, V streamed from L2)
    fused_pv<<<dim3(512, 1, 1), dim3(1024), 0, stream>>>(Sb, Vt, out);
}